// Round 2
// baseline (9019.341 us; speedup 1.0000x reference)
//
#include <hip/hip_runtime.h>

#define NROWS 2048
#define DR2   512
#define TSTEPS 64
#define NK    ((size_t)NROWS * DR2)          // elements per [N,512] slice
#define NWG   256                            // persistent grid: 1 WG/CU (128 KB LDS)
#define XGRP  32                             // WGs per per-XCD barrier counter (256/8)

typedef _Float16 half8 __attribute__((ext_vector_type(8)));
typedef float floatx4 __attribute__((ext_vector_type(4)));

// Async global->LDS, 16 B/lane. LDS base wave-uniform; HW scatters lane i at
// base + 16*i. Bank-conflict swizzle is applied on the GLOBAL address side.
static __device__ __forceinline__ void gload_lds16(const _Float16* g, _Float16* l) {
    __builtin_amdgcn_global_load_lds(
        (const __attribute__((address_space(1))) unsigned int*)g,
        (__attribute__((address_space(3))) unsigned int*)l,
        16, 0, 0);
}

// Wt[j][kk] = w1[kk][j], f16, j in [0,512), kk in [0,1024).
// kk<512 multiplies h (top), kk>=512 multiplies static (bottom).
// Also resets the grid-barrier counters.
__global__ void prep_w(const float* __restrict__ w1, _Float16* __restrict__ Wt,
                       unsigned* bar) {
    if (blockIdx.x == 0 && threadIdx.x < 272) bar[threadIdx.x] = 0u;
    int idx = blockIdx.x * 256 + threadIdx.x;   // = j*1024 + kk
    int kk = idx & 1023;
    int j  = idx >> 10;
    Wt[idx] = (_Float16)w1[kk * DR2 + j];
}

// h16 = (f16)h0 ; out0[0] = h0 (reference stores h0, NOT states[0])
__global__ void prep_h0(const float* __restrict__ h0, _Float16* __restrict__ h16,
                        float* __restrict__ out0) {
    int idx = blockIdx.x * 256 + threadIdx.x;   // per float4
    float4 v = ((const float4*)h0)[idx];
    ((float4*)out0)[idx] = v;
    union { uint2 u; _Float16 h[4]; } p;
    p.h[0] = (_Float16)v.x; p.h[1] = (_Float16)v.y;
    p.h[2] = (_Float16)v.z; p.h[3] = (_Float16)v.w;
    ((uint2*)h16)[idx] = p.u;
}

// ---------------------------------------------------------------------------
// Persistent kernel: all 64 recurrence steps in one launch, S fully fused.
// mm = [h | static_t] @ w1  (K=1024: phases 0-3 = h from f16 ping-pong via
// global_load_lds; phases 4-7 = static_t f32->f16 reg-staged).
// 256 WGs x 512 thr, 128 KB LDS => exactly 1 WG/CU, all co-resident.
// Per WG: output tile 128n x 32j; Wres = w1^T[j0:j0+32][0:1024] resident in
// LDS all 64 steps. One device-wide barrier per step (two-level atomic
// counters + per-thread release/acquire fences). Outputs are write-only
// (no aliasing, no overlays). Numerics match the verified per-step kernel:
// gate + dif use the f16-roundtripped h.
// ---------------------------------------------------------------------------
__global__ __launch_bounds__(512, 1) void run_steps(
    const float* __restrict__ thr,       // [T,N]
    const _Float16* __restrict__ Wt,     // [512][1024]
    const float* __restrict__ h0,        // [N,512] f32
    const float* __restrict__ sta,       // [T,N,512] f32
    _Float16* __restrict__ hb0,          // [N,512] f16 ping
    _Float16* __restrict__ hb1,          // [N,512] f16 pong
    float* __restrict__ out0, float* __restrict__ out1, float* __restrict__ out2,
    unsigned* bar)
{
    __shared__ _Float16 Wres[32 * 1024];     // 64 KB, resident all 64 steps
    __shared__ _Float16 Abuf[2][128 * 128];  // 2 x 32 KB, K-phase double buffer

    const int tid = threadIdx.x, lane = tid & 63, wv = tid >> 6;
    const int lm = lane & 15, quad = lane >> 4;

    // XCD-locality swizzle: the 16 j-blocks of each n-group land on one XCD,
    // so the 16x reuse of static_t / h rows is absorbed by the local L2.
    const int bid = blockIdx.x;
    const int xcd = bid & 7, loc = bid >> 3;       // loc 0..31
    const int by  = xcd * 2 + (loc >> 4);          // n-group 0..15
    const int bx  = loc & 15;                      // j-block 0..15
    const int j0  = bx * 32;
    const int n0  = by * 128;

    // one-time: full-W residency (32 j-rows x K=1024, swizzled global source)
    #pragma unroll
    for (int i = 0; i < 8; ++i) {
        int idx = i * 8 + wv;                      // 0..63
        int r = idx >> 1, hh = idx & 1;
        gload_lds16(Wt + (size_t)(j0 + r) * 1024 + hh * 512 + (lane ^ (r & 7)) * 8,
                    Wres + r * 1024 + hh * 512);
    }

    const int nb = n0 + wv * 16 + quad * 4;        // + r
    const int jb = j0 + lm;                        // + tj*16
    const int ra = wv * 16 + lm;                   // A row for MFMA reads
    float thv[4], thvn[4], hrv[2][4];
    #pragma unroll
    for (int r = 0; r < 4; ++r) {
        thv[r] = thr[nb + r];                      // t = 0
        #pragma unroll
        for (int tj = 0; tj < 2; ++tj)             // f16-roundtripped gate operand
            hrv[tj][r] = (float)(_Float16)h0[(size_t)(nb + r) * DR2 + jb + tj * 16];
    }

    const float DECAY = 0.60653065971263342f;

    #pragma unroll 1
    for (int t = 0; t < TSTEPS; ++t) {
        const _Float16* hcur = (t & 1) ? hb1 : hb0;
        _Float16*       hnx  = (t & 1) ? hb0 : hb1;
        const float*    stat = sta + (size_t)t * NK;

        // stage K-phase 0 of A (h rows n0..n0+127, K 0..127)
        #pragma unroll
        for (int i = 0; i < 4; ++i) {
            int rp = wv * 16 + i * 4;
            int r  = rp + (lane >> 4);
            int c  = (lane & 15) ^ (r & 7);
            gload_lds16(hcur + (size_t)(n0 + r) * DR2 + c * 8, &Abuf[0][rp * 128]);
        }
        __syncthreads();    // also drains Wres loads on t=0

        floatx4 acc[2] = {};

        #pragma unroll
        for (int p = 0; p < 8; ++p) {
            float4 pre[8];
            if (p < 3) {                           // prefetch next h phase
                #pragma unroll
                for (int i = 0; i < 4; ++i) {
                    int rp = wv * 16 + i * 4;
                    int r  = rp + (lane >> 4);
                    int c  = (lane & 15) ^ (r & 7);
                    gload_lds16(hcur + (size_t)(n0 + r) * DR2 + (p + 1) * 128 + c * 8,
                                &Abuf[(p + 1) & 1][rp * 128]);
                }
            } else if (p < 7) {                    // issue static f32 loads early
                #pragma unroll
                for (int q = 0; q < 4; ++q) {
                    int cidx = q * 512 + tid;      // 0..2047 = 128 rows x 16 chunks
                    int r = cidx >> 4, c16 = cidx & 15;
                    int k8 = c16 ^ (r & 7);
                    const float* g = stat + (size_t)(n0 + r) * DR2 + (p - 3) * 128 + k8 * 8;
                    pre[q * 2]     = *(const float4*)g;
                    pre[q * 2 + 1] = *(const float4*)(g + 4);
                }
            }
            if (p == 0 && t < TSTEPS - 1) {        // prefetch next-step thr
                #pragma unroll
                for (int r = 0; r < 4; ++r)
                    thvn[r] = thr[(t + 1) * NROWS + nb + r];
            }

            const _Float16* A = Abuf[p & 1];
            #pragma unroll
            for (int ks = 0; ks < 4; ++ks) {
                int c8 = ks * 4 + quad;            // phase-local chunk 0..15
                int cg = p * 16 + c8;              // global K chunk 0..127
                half8 a  = *(const half8*)(A + ra * 128 + ((c8 ^ (ra & 7)) << 3));
                half8 b0 = *(const half8*)(Wres + lm * 1024 + ((cg ^ (lm & 7)) << 3));
                half8 b1 = *(const half8*)(Wres + (lm + 16) * 1024 + ((cg ^ (lm & 7)) << 3));
                acc[0] = __builtin_amdgcn_mfma_f32_16x16x32_f16(a, b0, acc[0], 0, 0, 0);
                acc[1] = __builtin_amdgcn_mfma_f32_16x16x32_f16(a, b1, acc[1], 0, 0, 0);
            }

            if (p >= 3 && p < 7) {                 // cvt + ds_write static phase
                #pragma unroll
                for (int q = 0; q < 4; ++q) {
                    int cidx = q * 512 + tid;
                    int r = cidx >> 4, c16 = cidx & 15;
                    float4 lo = pre[q * 2], hi = pre[q * 2 + 1];
                    union { half8 v; _Float16 h[8]; } u;
                    u.h[0]=(_Float16)lo.x; u.h[1]=(_Float16)lo.y;
                    u.h[2]=(_Float16)lo.z; u.h[3]=(_Float16)lo.w;
                    u.h[4]=(_Float16)hi.x; u.h[5]=(_Float16)hi.y;
                    u.h[6]=(_Float16)hi.z; u.h[7]=(_Float16)hi.w;
                    *(half8*)(&Abuf[(p + 1) & 1][r * 128 + (c16 << 3)]) = u.v;
                }
            }
            if (p < 7) __syncthreads();
        }

        // epilogue: gate; all outputs written immediately (pure, no aliasing)
        #pragma unroll
        for (int r = 0; r < 4; ++r) {
            float th = thv[r], om = 1.0f - th;
            #pragma unroll
            for (int tj = 0; tj < 2; ++tj) {
                float z  = acc[tj][r] * th + hrv[tj][r] * om;
                float hn = DECAY / (1.0f + __expf(-z));
                _Float16 h16 = (_Float16)hn;
                hnx[(size_t)(nb + r) * DR2 + jb + tj * 16] = h16;
                if (t >= 1) {
                    size_t o = ((size_t)t * NROWS + nb + r) * DR2 + jb + tj * 16;
                    __builtin_nontemporal_store(hn, out0 + o);
                    __builtin_nontemporal_store(hn - hrv[tj][r], out2 + (o - NK));
                }
                if (t == TSTEPS - 1)
                    __builtin_nontemporal_store(
                        hn, out1 + (size_t)(nb + r) * DR2 + jb + tj * 16);
                hrv[tj][r] = (float)h16;           // f16-roundtripped carry
            }
            if (t < TSTEPS - 1) thv[r] = thvn[r];
        }

        // ---- device-wide barrier (two-level, monotonic counters) ----
        if (t < TSTEPS - 1) {
            __threadfence();                       // release (every thread)
            __syncthreads();
            if (tid == 0) {
                unsigned old = __hip_atomic_fetch_add(&bar[xcd * 32], 1u,
                                   __ATOMIC_ACQ_REL, __HIP_MEMORY_SCOPE_AGENT);
                if (old == (unsigned)(XGRP * (t + 1) - 1))      // last in group
                    __hip_atomic_fetch_add(&bar[256], 1u,
                        __ATOMIC_ACQ_REL, __HIP_MEMORY_SCOPE_AGENT);
                while (__hip_atomic_load(&bar[256], __ATOMIC_RELAXED,
                                         __HIP_MEMORY_SCOPE_AGENT)
                       < (unsigned)(8 * (t + 1)))
                    __builtin_amdgcn_s_sleep(2);
            }
            __syncthreads();
            __threadfence();                       // acquire (every thread)
        }
    }
}

extern "C" void kernel_launch(void* const* d_in, const int* in_sizes, int n_in,
                              void* d_out, int out_size, void* d_ws, size_t ws_size,
                              hipStream_t stream) {
    const float* d_static = (const float*)d_in[0];
    const float* d_thr    = (const float*)d_in[1];
    const float* d_h0     = (const float*)d_in[2];
    const float* d_w1     = (const float*)d_in[3];

    float* out0 = (float*)d_out;                       // [64,2048,512]
    float* out1 = out0 + (size_t)TSTEPS * NK;          // [2048,512]
    float* out2 = out1 + NK;                           // [63,2048,512]

    _Float16* Wt    = (_Float16*)d_ws;                 // 1 MB
    _Float16* hbuf0 = Wt + (size_t)DR2 * 1024;         // 2 MB
    _Float16* hbuf1 = hbuf0 + NK;                      // 2 MB

    // barrier counters: workspace tail if it fits, else tail of out1 (those
    // elements are rewritten at t=63, after the last barrier use at t=62)
    size_t need = (size_t)DR2 * 1024 * 2 + 4 * NK + 2048;
    unsigned* bar = (ws_size >= need) ? (unsigned*)(hbuf1 + NK)
                                      : (unsigned*)(out1 + NK - 512);

    prep_w<<<2048, 256, 0, stream>>>(d_w1, Wt, bar);
    prep_h0<<<1024, 256, 0, stream>>>(d_h0, hbuf0, out0);
    run_steps<<<NWG, 512, 0, stream>>>(d_thr, Wt, d_h0, d_static,
                                       hbuf0, hbuf1, out0, out1, out2, bar);
}